// Round 11
// baseline (341.911 us; speedup 1.0000x reference)
//
#include <hip/hip_runtime.h>
#include <hip/hip_cooperative_groups.h>
#include <stdint.h>

namespace cg = cooperative_groups;

// ---------------------------------------------------------------------------
// RPN anchor-target layer for MI355X — round 11: ONE cooperative kernel.
//
// Verified invariants (R6-R10):
//  * ALL IoU math via ONE noinline compiled copy (iou_core + box_area_f) =>
//    bit-identical across call sites (is_best float-equality). DO NOT inline.
//  * JAX partitionable threefry; composite key (m<<16)|(65535-n), n = the
//    ORIGINAL anchor index (h*W+w)*9+a. Keys strictly distinct.
//  * Inside-anchor set == 9 runtime rectangles; compact-candidate selection.
//
// Change vs R10 (pass, 137 us, neutral micro-opts => launch/gap-bound):
//  * Phases gtmax -> fuse -> select -> out fused into one cooperative launch
//    with grid.sync() between phases. 576 blocks x 256 thr (co-resident:
//    16.4 KB LDS union -> 9 blocks/CU possible, need 2.25).
// ---------------------------------------------------------------------------

#define B_   16
#define A_   9
#define H_   64
#define W_   64
#define HW_  (H_*W_)
#define N_   (HW_*A_)      // 36864
#define KG_  50
#define S0_  (B_*A_*HW_)   // labels elems
#define S1_  (B_*4*A_*HW_) // targets / in_w / out_w elems
#define NGTB_ (B_*KG_)     // phase-1 virtual blocks
#define NFB_  (B_*73)      // phase-2 virtual blocks (73*256 = 18688 >= C)
#define GRID_ 576          // real blocks ( == S0_/4/256, phase-4 1:1 )
#define CAP_  20480        // per-(batch,phase) candidate cap (max 18624)
#define NHIST_ (B_*2*256 + B_*2)   // hist + cnt ints to clear

typedef unsigned long long ull;

// base anchors from generate_anchors() (exact: all half-integers cancel)
__constant__ float c_base[A_][4] = {
  { -84.f,  -40.f,  99.f,  55.f},
  {-176.f,  -88.f, 191.f, 103.f},
  {-360.f, -184.f, 375.f, 199.f},
  { -56.f,  -56.f,  71.f,  71.f},
  {-120.f, -120.f, 135.f, 135.f},
  {-248.f, -248.f, 263.f, 263.f},
  { -36.f,  -80.f,  51.f,  95.f},
  { -80.f, -168.f,  95.f, 183.f},
  {-168.f, -344.f, 183.f, 359.f},
};

__device__ __forceinline__ void tf2x32(uint32_t k0, uint32_t k1,
                                       uint32_t x0, uint32_t x1,
                                       uint32_t& o0, uint32_t& o1) {
  const uint32_t ks2 = k0 ^ k1 ^ 0x1BD11BDAu;
  uint32_t ks[3] = {k0, k1, ks2};
  x0 += ks[0]; x1 += ks[1];
  const int R[2][4] = {{13,15,26,6},{17,29,16,24}};
  #pragma unroll
  for (int i = 0; i < 5; i++) {
    #pragma unroll
    for (int j = 0; j < 4; j++) {
      x0 += x1;
      int r = R[i & 1][j];
      x1 = (x1 << r) | (x1 >> (32 - r));
      x1 ^= x0;
    }
    x0 += ks[(i + 1) % 3];
    x1 += ks[(i + 2) % 3] + (uint32_t)(i + 1);
  }
  o0 = x0; o1 = x1;
}

// Shared noinline numerics: single compiled copy each => bit-identity across
// all call sites by construction. contract(off) as belt-and-braces.
__device__ __attribute__((noinline))
float box_area_f(float x1, float y1, float x2, float y2) {
#pragma clang fp contract(off)
  return (x2 - x1 + 1.f) * (y2 - y1 + 1.f);
}

__device__ __attribute__((noinline))
float iou_core(float ax1, float ay1, float ax2, float ay2, float aarea,
               float gx1, float gy1, float gx2, float gy2, float garea) {
#pragma clang fp contract(off)
  float ix = fmaxf(fminf(ax2, gx2) - fmaxf(ax1, gx1) + 1.f, 0.f);
  float iy = fmaxf(fminf(ay2, gy2) - fmaxf(ay1, gy1) + 1.f, 0.f);
  float inter = ix * iy;
  return inter / (aarea + garea - inter);
}

// ---------------------------------------------------------------------------
__global__ __launch_bounds__(256) void k_mega(const float* __restrict__ gtb,
                                              const float* __restrict__ iminfo,
                                              float* __restrict__ out,
                                              int* __restrict__ packed,
                                              float* __restrict__ gt_max,
                                              float* __restrict__ uw,
                                              uint32_t* __restrict__ keys,
                                              int* __restrict__ cnt,
                                              int* __restrict__ hist,
                                              ull* __restrict__ Kstar,
                                              ull* __restrict__ cand) {
  cg::grid_group grid = cg::this_grid();
  const int tid = threadIdx.x;
  const int bid = blockIdx.x;

  __shared__ union {
    struct {
      float sgx1[KG_], sgy1[KG_], sgx2[KG_], sgy2[KG_], sga[KG_], sgm[KG_];
      int xlo[A_], ylo[A_], nx[A_], pre[A_ + 1];
      uint32_t k[4];
      int num[2], base[2];
    } f;                                  // phase 2
    struct {
      ull keys2[2048];
      int bin, r, n;
    } s;                                  // phase 3
    float sw[4];                          // phase 1 reduce
  } sh;

  const float imh = iminfo[0], imw = iminfo[1];

  // ---- phase 0/1: keys + clear cnt/hist + gt_max ------------------------
  if (bid == 0 && tid < B_) {
    uint32_t k0, k1, kf0, kf1, kb0, kb1;
    tf2x32(0u, 42u, 0u, (uint32_t)tid, k0, k1);  // split(root,16)[b]
    tf2x32(k0, k1, 0u, 0u, kf0, kf1);            // kf
    tf2x32(k0, k1, 0u, 1u, kb0, kb1);            // kb
    keys[tid * 4 + 0] = kf0;
    keys[tid * 4 + 1] = kf1;
    keys[tid * 4 + 2] = kb0;
    keys[tid * 4 + 3] = kb1;
  }
  if (bid < 32) {
    const int per = (NHIST_ + 31) / 32;
    const int base = bid * per;
    const int lim = min(base + per, NHIST_);
    for (int i = base + tid; i < lim; i += 256) cnt[i] = 0;  // cnt then hist
  }
  for (int vb = bid; vb < NGTB_; vb += GRID_) {
    const int b = vb / KG_;
    const int g = vb % KG_;
    const float* gp = gtb + (b * KG_ + g) * 5;
    const float gx1 = gp[0], gy1 = gp[1], gx2 = gp[2], gy2 = gp[3];
    const float garea = box_area_f(gx1, gy1, gx2, gy2);
    float best = 0.f;
    for (int a = 0; a < A_; a++) {
      const float bx1 = c_base[a][0], by1 = c_base[a][1];
      const float bx2 = c_base[a][2], by2 = c_base[a][3];
      const float aarea = box_area_f(bx1, by1, bx2, by2);  // == shifted
      int xlo = max(0, (int)ceilf(-bx1 / 16.f));
      int xhi = min(W_ - 1, (int)ceilf((imw - bx2) / 16.f) - 1);
      int ylo = max(0, (int)ceilf(-by1 / 16.f));
      int yhi = min(H_ - 1, (int)ceilf((imh - by2) / 16.f) - 1);
      xlo = max(xlo, (int)floorf((gx1 - 1.f - bx2) / 16.f));
      xhi = min(xhi, (int)ceilf((gx2 + 1.f - bx1) / 16.f));
      ylo = max(ylo, (int)floorf((gy1 - 1.f - by2) / 16.f));
      yhi = min(yhi, (int)ceilf((gy2 + 1.f - by1) / 16.f));
      const int nx = xhi - xlo + 1, ny = yhi - ylo + 1;
      if (nx <= 0 || ny <= 0) continue;
      const int lw = (nx <= 1) ? 0 : (32 - __clz(nx - 1));  // 2^lw >= nx
      const int tot = ny << lw;
      const int mask = (1 << lw) - 1;
      for (int t = tid; t < tot; t += 256) {
        const int xi = t & mask;
        if (xi >= nx) continue;
        const int x = xlo + xi;
        const int y = ylo + (t >> lw);
        const float sx = 16.f * (float)x, sy = 16.f * (float)y;
        best = fmaxf(best, iou_core(bx1 + sx, by1 + sy, bx2 + sx, by2 + sy,
                                    aarea, gx1, gy1, gx2, gy2, garea));
      }
    }
    best = fmaxf(best, __shfl_xor(best, 32));
    best = fmaxf(best, __shfl_xor(best, 16));
    best = fmaxf(best, __shfl_xor(best, 8));
    best = fmaxf(best, __shfl_xor(best, 4));
    best = fmaxf(best, __shfl_xor(best, 2));
    best = fmaxf(best, __shfl_xor(best, 1));
    if ((tid & 63) == 0) sh.sw[tid >> 6] = best;
    __syncthreads();
    if (tid == 0)
      gt_max[b * KG_ + g] = fmaxf(fmaxf(sh.sw[0], sh.sw[1]),
                                  fmaxf(sh.sw[2], sh.sw[3]));
    __syncthreads();
  }

  grid.sync();

  // ---- phase 2: fused labels + candidate compaction ---------------------
  for (int vb = bid; vb < NFB_; vb += GRID_) {
    const int b = vb / 73;
    const int chunk = vb % 73;
    __syncthreads();                       // protect LDS from prior iteration
    if (tid < KG_) {
      const float* g = gtb + (b * KG_ + tid) * 5;
      float x1 = g[0], y1 = g[1], x2 = g[2], y2 = g[3];
      sh.f.sgx1[tid] = x1; sh.f.sgy1[tid] = y1;
      sh.f.sgx2[tid] = x2; sh.f.sgy2[tid] = y2;
      sh.f.sga[tid] = box_area_f(x1, y1, x2, y2);
      float gm = gt_max[b * KG_ + tid];
      sh.f.sgm[tid] = (gm == 0.f) ? 1e-5f : gm;
    }
    if (tid < 4) sh.f.k[tid] = keys[b * 4 + tid];
    if (tid < 2) sh.f.num[tid] = 0;
    if (tid < A_) {
      const float bx1 = c_base[tid][0], by1 = c_base[tid][1];
      const float bx2 = c_base[tid][2], by2 = c_base[tid][3];
      int xlo = max(0, (int)ceilf(-bx1 / 16.f));
      int xhi = min(W_ - 1, (int)ceilf((imw - bx2) / 16.f) - 1);
      int ylo = max(0, (int)ceilf(-by1 / 16.f));
      int yhi = min(H_ - 1, (int)ceilf((imh - by2) / 16.f) - 1);
      int nx = max(0, xhi - xlo + 1), ny = max(0, yhi - ylo + 1);
      sh.f.xlo[tid] = xlo; sh.f.ylo[tid] = ylo; sh.f.nx[tid] = nx;
      sh.f.pre[tid + 1] = nx * ny;
    }
    __syncthreads();
    if (tid == 0) {
      sh.f.pre[0] = 0;
      for (int a = 0; a < A_; a++) sh.f.pre[a + 1] += sh.f.pre[a];
    }
    __syncthreads();
    const int C = sh.f.pre[A_];
    const int t = chunk * 256 + tid;
    bool act = false;
    int p = 0, lpos = 0, n = 0;
    uint32_t m = 0;
    if (t < C) {
      int a = 0;
      while (t >= sh.f.pre[a + 1]) a++;
      const int idx = t - sh.f.pre[a];
      const int nx = sh.f.nx[a];
      const int y = sh.f.ylo[a] + idx / nx;
      const int x = sh.f.xlo[a] + (idx - (idx / nx) * nx);
      n = (y * W_ + x) * A_ + a;                 // ORIGINAL index (RNG order)
      const int n2 = a * HW_ + y * W_ + x;       // output-layout index
      const float sx = 16.f * (float)x, sy = 16.f * (float)y;
      const float ax1 = c_base[a][0] + sx, ay1 = c_base[a][1] + sy;
      const float ax2 = c_base[a][2] + sx, ay2 = c_base[a][3] + sy;
      const float aarea = box_area_f(c_base[a][0], c_base[a][1],
                                     c_base[a][2], c_base[a][3]);  // == shifted
      float mo = -1.f;
      int bidx = 0;
      bool best = false;
      for (int k = 0; k < KG_; k++) {
        float ovr = iou_core(ax1, ay1, ax2, ay2, aarea,
                             sh.f.sgx1[k], sh.f.sgy1[k],
                             sh.f.sgx2[k], sh.f.sgy2[k], sh.f.sga[k]);
        if (ovr > mo) { mo = ovr; bidx = k; }    // first-argmax (matches jnp)
        best = best || (ovr == sh.f.sgm[k]);
      }
      int lab = -1;
      if (mo < 0.3f) lab = 0;
      if (best || mo >= 0.7f) lab = 1;
      packed[(size_t)b * N_ + n2] = (bidx << 2) | (lab + 1);
      if (lab >= 0) {
        act = true;
        p = (lab == 1) ? 0 : 1;
        uint32_t y0, y1;
        tf2x32(sh.f.k[2 * p], sh.f.k[2 * p + 1], 0u, (uint32_t)n, y0, y1);
        m = (y0 ^ y1) >> 9;
        lpos = atomicAdd(&sh.f.num[p], 1);
      }
    }
    __syncthreads();
    if (tid < 2 && sh.f.num[tid] > 0)
      sh.f.base[tid] = atomicAdd(&cnt[b * 2 + tid], sh.f.num[tid]);
    __syncthreads();
    if (act) {
      cand[(size_t)(b * 2 + p) * CAP_ + sh.f.base[p] + lpos] =
          ((ull)m << 16) | (ull)(65535 - n);
      atomicAdd(&hist[(b * 2 + p) * 256 + (int)(m >> 15)], 1);
    }
  }

  grid.sync();

  // ---- phase 3: cutoff K* per (b,phase) on blocks 0..31 -----------------
  if (bid < B_ * 2) {
    const int b = bid >> 1, p = bid & 1;
    const int cf = cnt[b * 2 + 0], cb = cnt[b * 2 + 1];
    const int limit = (p == 0) ? 128 : 256 - min(cf, 128);
    const int c = (p == 0) ? cf : cb;
    if (p == 1 && tid == 0) {
      int kf = min(cf, 128);
      int kb = min(cb, 256 - kf);
      uw[b] = 1.f / (float)(kf + kb);
    }
    if (c <= limit) {
      if (tid == 0) Kstar[b * 2 + p] = 0ull;   // keep all (keys always > 0)
    } else {
      if (tid == 0) {
        const int* Hh = hist + (b * 2 + p) * 256;
        int acc = 0, bin = 255, r = 0;
        for (; bin >= 0; bin--) {
          int hv = Hh[bin];
          if (acc + hv >= limit) { r = limit - acc; break; }
          acc += hv;
        }
        sh.s.bin = bin; sh.s.r = r; sh.s.n = 0;
      }
      __syncthreads();
      const uint32_t bin0 = (uint32_t)sh.s.bin;
      const int r0 = sh.s.r;                   // 1-based rank within bin
      const ull* C = cand + (size_t)(b * 2 + p) * CAP_;
      for (int i = tid; i < c; i += 256) {
        ull k = C[i];
        if ((uint32_t)(k >> 31) == bin0) {     // key bits 31..38 == m>>15
          int pos = atomicAdd(&sh.s.n, 1);
          if (pos < 2048) sh.s.keys2[pos] = k;
        }
      }
      __syncthreads();
      const int s = min(sh.s.n, 2048);
      for (int j = tid; j < s; j += 256) {
        ull kj = sh.s.keys2[j];
        int rank = 0;
        for (int q = 0; q < s; q++) rank += (sh.s.keys2[q] > kj) ? 1 : 0;
        if (rank == r0 - 1) Kstar[b * 2 + p] = kj;  // unique writer
      }
    }
  }

  grid.sync();

  // ---- phase 4: outputs, vectorized x4, folded disable ------------------
  {
    const int gid = bid * 256 + tid;            // 0 .. S0_/4-1 exactly
    const int e = gid * 4;
    const int w0 = e & 63;
    const int h = (e >> 6) & 63;
    const int a = (e >> 12) % A_;
    const int b = e / (A_ * HW_);

    const float ay1 = c_base[a][1] + 16.f * (float)h;
    const float ay2 = c_base[a][3] + 16.f * (float)h;
    const bool insY = (ay1 >= 0.f) && (ay2 < imh);

    const int4 pk4 = *(const int4*)(packed + e);
    const int pk[4] = {pk4.x, pk4.y, pk4.z, pk4.w};
    const float uwb = uw[b];
    const ull KF_ = Kstar[b * 2 + 0];
    const ull KB_ = Kstar[b * 2 + 1];
    const uint32_t kf0 = keys[b * 4 + 0], kf1 = keys[b * 4 + 1];
    const uint32_t kb0 = keys[b * 4 + 2], kb1 = keys[b * 4 + 3];

    float4 lab4, tx4, ty4, tw4, th4, inw4, oww4;
    float* labp = (float*)&lab4;
    float* txp = (float*)&tx4; float* typ = (float*)&ty4;
    float* twp = (float*)&tw4; float* thp = (float*)&th4;
    float* inwp = (float*)&inw4; float* owwp = (float*)&oww4;

    #pragma unroll
    for (int j = 0; j < 4; j++) {
      const int w = w0 + j;
      const float ax1 = c_base[a][0] + 16.f * (float)w;
      const float ax2 = c_base[a][2] + 16.f * (float)w;
      const bool ins = insY && (ax1 >= 0.f) && (ax2 < imw);
      int lab = (pk[j] & 3) - 1;
      const int g = pk[j] >> 2;
      float tx = 0.f, ty = 0.f, tw = 0.f, th = 0.f;
      if (ins) {
        if (lab >= 0) {                        // folded disable
          const int n = (h * W_ + w) * A_ + a; // ORIGINAL index for RNG
          const int p = (lab == 1) ? 0 : 1;
          uint32_t y0, y1;
          tf2x32(p ? kb0 : kf0, p ? kb1 : kf1, 0u, (uint32_t)n, y0, y1);
          ull key = ((ull)((y0 ^ y1) >> 9) << 16) | (ull)(65535 - n);
          if (key < (p ? KB_ : KF_)) lab = -1;
        }
        const float* gp = gtb + ((size_t)b * KG_ + g) * 5;
        float aw = ax2 - ax1 + 1.f, ah = ay2 - ay1 + 1.f;
        float acx = ax1 + 0.5f * (aw - 1.f), acy = ay1 + 0.5f * (ah - 1.f);
        float gw = gp[2] - gp[0] + 1.f, gh = gp[3] - gp[1] + 1.f;
        float gcx = gp[0] + 0.5f * (gw - 1.f), gcy = gp[1] + 0.5f * (gh - 1.f);
        tx = (gcx - acx) / aw;
        ty = (gcy - acy) / ah;
        tw = logf(gw / aw);
        th = logf(gh / ah);
      }
      labp[j] = ins ? (float)lab : 0.f;
      txp[j] = tx; typ[j] = ty; twp[j] = tw; thp[j] = th;
      inwp[j] = (ins && lab == 1) ? 1.f : 0.f;
      owwp[j] = (ins && lab >= 0) ? uwb : 0.f;
    }

    *(float4*)(out + e) = lab4;                 // labels (B,1,A*H,W)
    float* o1 = out + S0_;
    const size_t toff = (size_t)b * (4 * A_ * HW_) + (4 * a) * HW_ + h * W_ + w0;
    *(float4*)(o1 + toff)           = tx4;
    *(float4*)(o1 + toff + HW_)     = ty4;
    *(float4*)(o1 + toff + 2 * HW_) = tw4;
    *(float4*)(o1 + toff + 3 * HW_) = th4;
    float* o2 = out + S0_ + S1_;
    *(float4*)(o2 + toff)           = inw4;
    *(float4*)(o2 + toff + HW_)     = inw4;
    *(float4*)(o2 + toff + 2 * HW_) = inw4;
    *(float4*)(o2 + toff + 3 * HW_) = inw4;
    float* o3 = out + S0_ + 2 * (size_t)S1_;
    *(float4*)(o3 + toff)           = oww4;
    *(float4*)(o3 + toff + HW_)     = oww4;
    *(float4*)(o3 + toff + 2 * HW_) = oww4;
    *(float4*)(o3 + toff + 3 * HW_) = oww4;
  }
}

// ---------------------------------------------------------------------------
extern "C" void kernel_launch(void* const* d_in, const int* in_sizes, int n_in,
                              void* d_out, int out_size, void* d_ws, size_t ws_size,
                              hipStream_t stream) {
  const float* gtb = (const float*)d_in[1];     // gt_boxes (B,50,5)
  const float* iminfo = (const float*)d_in[2];  // im_info  (B,2)
  float* out = (float*)d_out;

  // workspace layout (~7.9 MB); every segment is 8B-aligned.
  int* packed = (int*)d_ws;                          // B*N
  float* gt_max = (float*)(packed + (size_t)B_ * N_);// B*KG (3200 B)
  float* uw = gt_max + B_ * KG_;                     // B    (64 B)
  uint32_t* keys = (uint32_t*)(uw + B_);             // B*4  (256 B)
  int* cnt = (int*)(keys + B_ * 4);                  // B*2  (128 B)
  int* hist = cnt + B_ * 2;                          // B*2*256 (32 KB)
  ull* Kstar = (ull*)(hist + B_ * 2 * 256);          // B*2  (256 B)
  ull* cand = Kstar + B_ * 2;                        // B*2*CAP (5.2 MB)

  void* args[] = {
    (void*)&gtb, (void*)&iminfo, (void*)&out, (void*)&packed,
    (void*)&gt_max, (void*)&uw, (void*)&keys, (void*)&cnt,
    (void*)&hist, (void*)&Kstar, (void*)&cand,
  };
  hipLaunchCooperativeKernel((const void*)k_mega, dim3(GRID_), dim3(256),
                             args, 0, stream);
}

// Round 12
// 233.382 us; speedup vs baseline: 1.4650x; 1.4650x over previous
//
#include <hip/hip_runtime.h>
#include <stdint.h>

// ---------------------------------------------------------------------------
// RPN anchor-target layer for MI355X — round 12.
//
// R11 lesson (measured): grid.sync() costs ~65-70 us EACH on MI355X (8 XCDs,
// cross-XCD L2 flush) — stream-ordered launches are ~10x cheaper. Reverted.
//
// Structure = R10 (137 us) minus the k_select launch: selection is folded
// into k_fuse via the LAST-ARRIVAL pattern (threadfence + device-scope
// atomic done-counter; the 73rd block of each batch runs selection for that
// batch). No waiting, no co-residency assumption, no grid sync.
//
// Verified invariants (R6-R10):
//  * ALL IoU math via ONE noinline compiled copy (iou_core + box_area_f) =>
//    bit-identical across call sites (is_best float-equality). DO NOT inline.
//  * JAX partitionable threefry; composite key (m<<16)|(65535-n), n = the
//    ORIGINAL anchor index (h*W+w)*9+a. Keys strictly distinct.
//  * Inside-anchor set == 9 runtime rectangles; compact-candidate selection.
// ---------------------------------------------------------------------------

#define B_   16
#define A_   9
#define H_   64
#define W_   64
#define HW_  (H_*W_)
#define N_   (HW_*A_)      // 36864
#define KG_  50
#define S0_  (B_*A_*HW_)   // labels elems
#define S1_  (B_*4*A_*HW_) // targets / in_w / out_w elems
#define NGTB_ (B_*KG_)     // k_gtmax blocks
#define FB_   73           // k_fuse blocks per batch (73*256 = 18688 >= C@1024)
#define CAP_  20480        // per-(batch,phase) candidate cap (max 18624)
#define NCLR_ (B_*2*256 + B_*2 + B_)   // hist + cnt + done ints to clear

typedef unsigned long long ull;

// base anchors from generate_anchors() (exact: all half-integers cancel)
__constant__ float c_base[A_][4] = {
  { -84.f,  -40.f,  99.f,  55.f},
  {-176.f,  -88.f, 191.f, 103.f},
  {-360.f, -184.f, 375.f, 199.f},
  { -56.f,  -56.f,  71.f,  71.f},
  {-120.f, -120.f, 135.f, 135.f},
  {-248.f, -248.f, 263.f, 263.f},
  { -36.f,  -80.f,  51.f,  95.f},
  { -80.f, -168.f,  95.f, 183.f},
  {-168.f, -344.f, 183.f, 359.f},
};

__device__ __forceinline__ void tf2x32(uint32_t k0, uint32_t k1,
                                       uint32_t x0, uint32_t x1,
                                       uint32_t& o0, uint32_t& o1) {
  const uint32_t ks2 = k0 ^ k1 ^ 0x1BD11BDAu;
  uint32_t ks[3] = {k0, k1, ks2};
  x0 += ks[0]; x1 += ks[1];
  const int R[2][4] = {{13,15,26,6},{17,29,16,24}};
  #pragma unroll
  for (int i = 0; i < 5; i++) {
    #pragma unroll
    for (int j = 0; j < 4; j++) {
      x0 += x1;
      int r = R[i & 1][j];
      x1 = (x1 << r) | (x1 >> (32 - r));
      x1 ^= x0;
    }
    x0 += ks[(i + 1) % 3];
    x1 += ks[(i + 2) % 3] + (uint32_t)(i + 1);
  }
  o0 = x0; o1 = x1;
}

// Shared noinline numerics: single compiled copy each => bit-identity across
// all call sites by construction. contract(off) as belt-and-braces.
__device__ __attribute__((noinline))
float box_area_f(float x1, float y1, float x2, float y2) {
#pragma clang fp contract(off)
  return (x2 - x1 + 1.f) * (y2 - y1 + 1.f);
}

__device__ __attribute__((noinline))
float iou_core(float ax1, float ay1, float ax2, float ay2, float aarea,
               float gx1, float gy1, float gx2, float gy2, float garea) {
#pragma clang fp contract(off)
  float ix = fmaxf(fminf(ax2, gx2) - fmaxf(ax1, gx1) + 1.f, 0.f);
  float iy = fmaxf(fminf(ay2, gy2) - fmaxf(ay1, gy1) + 1.f, 0.f);
  float inter = ix * iy;
  return inter / (aarea + garea - inter);
}

// ---------------------------------------------------------------------------
// K1 (R10 verbatim + done-clear): gt_max, pruned to overlap∩inside rect.
__global__ __launch_bounds__(256) void k_gtmax(const float* __restrict__ gtb,
                                               const float* __restrict__ iminfo,
                                               float* __restrict__ gt_max,
                                               uint32_t* __restrict__ keys,
                                               int* __restrict__ cnt_hist) {
  const int b = blockIdx.x / KG_;
  const int g = blockIdx.x % KG_;
  const int tid = threadIdx.x;
  if (blockIdx.x == 0 && tid < B_) {
    uint32_t k0, k1, kf0, kf1, kb0, kb1;
    tf2x32(0u, 42u, 0u, (uint32_t)tid, k0, k1);  // split(root,16)[b]
    tf2x32(k0, k1, 0u, 0u, kf0, kf1);            // kf
    tf2x32(k0, k1, 0u, 1u, kb0, kb1);            // kb
    keys[tid * 4 + 0] = kf0;
    keys[tid * 4 + 1] = kf1;
    keys[tid * 4 + 2] = kb0;
    keys[tid * 4 + 3] = kb1;
  }
  if (blockIdx.x < 32) {
    const int per = (NCLR_ + 31) / 32;
    const int base = blockIdx.x * per;
    const int lim = min(base + per, NCLR_);
    for (int i = base + tid; i < lim; i += 256) cnt_hist[i] = 0;
  }
  const float* gp = gtb + (b * KG_ + g) * 5;
  const float gx1 = gp[0], gy1 = gp[1], gx2 = gp[2], gy2 = gp[3];
  const float garea = box_area_f(gx1, gy1, gx2, gy2);
  const float imh = iminfo[0], imw = iminfo[1];
  float best = 0.f;
  for (int a = 0; a < A_; a++) {
    const float bx1 = c_base[a][0], by1 = c_base[a][1];
    const float bx2 = c_base[a][2], by2 = c_base[a][3];
    const float aarea = box_area_f(bx1, by1, bx2, by2);  // == shifted (exact)
    int xlo = max(0, (int)ceilf(-bx1 / 16.f));
    int xhi = min(W_ - 1, (int)ceilf((imw - bx2) / 16.f) - 1);
    int ylo = max(0, (int)ceilf(-by1 / 16.f));
    int yhi = min(H_ - 1, (int)ceilf((imh - by2) / 16.f) - 1);
    xlo = max(xlo, (int)floorf((gx1 - 1.f - bx2) / 16.f));
    xhi = min(xhi, (int)ceilf((gx2 + 1.f - bx1) / 16.f));
    ylo = max(ylo, (int)floorf((gy1 - 1.f - by2) / 16.f));
    yhi = min(yhi, (int)ceilf((gy2 + 1.f - by1) / 16.f));
    const int nx = xhi - xlo + 1, ny = yhi - ylo + 1;
    if (nx <= 0 || ny <= 0) continue;
    const int lw = (nx <= 1) ? 0 : (32 - __clz(nx - 1));  // 2^lw >= nx
    const int tot = ny << lw;
    const int mask = (1 << lw) - 1;
    for (int t = tid; t < tot; t += 256) {
      const int xi = t & mask;
      if (xi >= nx) continue;
      const int x = xlo + xi;
      const int y = ylo + (t >> lw);
      const float sx = 16.f * (float)x, sy = 16.f * (float)y;
      best = fmaxf(best, iou_core(bx1 + sx, by1 + sy, bx2 + sx, by2 + sy,
                                  aarea, gx1, gy1, gx2, gy2, garea));
    }
  }
  best = fmaxf(best, __shfl_xor(best, 32));
  best = fmaxf(best, __shfl_xor(best, 16));
  best = fmaxf(best, __shfl_xor(best, 8));
  best = fmaxf(best, __shfl_xor(best, 4));
  best = fmaxf(best, __shfl_xor(best, 2));
  best = fmaxf(best, __shfl_xor(best, 1));
  __shared__ float sw[4];
  if ((tid & 63) == 0) sw[tid >> 6] = best;
  __syncthreads();
  if (tid == 0)
    gt_max[b * KG_ + g] = fmaxf(fmaxf(sw[0], sw[1]), fmaxf(sw[2], sw[3]));
}

// ---------------------------------------------------------------------------
// K2: fused labels + candidate compaction (R10 verbatim) + LAST-ARRIVAL
// selection: the 73rd finishing block of each batch computes K*/uw for it.
__global__ __launch_bounds__(256) void k_fuse(const float* __restrict__ gtb,
                                              const float* __restrict__ iminfo,
                                              const float* __restrict__ gt_max,
                                              const uint32_t* __restrict__ keys,
                                              int* __restrict__ packed,
                                              ull* __restrict__ cand,
                                              int* __restrict__ cnt,
                                              int* __restrict__ hist,
                                              int* __restrict__ done,
                                              ull* __restrict__ Kstar,
                                              float* __restrict__ uw) {
  __shared__ float sgx1[KG_], sgy1[KG_], sgx2[KG_], sgy2[KG_], sga[KG_], sgm[KG_];
  __shared__ int s_xlo[A_], s_ylo[A_], s_nx[A_], s_pre[A_ + 1];
  __shared__ uint32_t s_k[4];
  __shared__ int s_num[2], s_base[2];
  __shared__ ull s_keys[2048];
  __shared__ int s_bin, s_r, s_n, s_last;
  const int b = blockIdx.y;
  const int tid = threadIdx.x;
  if (tid < KG_) {
    const float* g = gtb + (b * KG_ + tid) * 5;
    float x1 = g[0], y1 = g[1], x2 = g[2], y2 = g[3];
    sgx1[tid] = x1; sgy1[tid] = y1; sgx2[tid] = x2; sgy2[tid] = y2;
    sga[tid] = box_area_f(x1, y1, x2, y2);
    float gm = gt_max[b * KG_ + tid];
    sgm[tid] = (gm == 0.f) ? 1e-5f : gm;
  }
  if (tid < 4) s_k[tid] = keys[b * 4 + tid];
  if (tid < A_) {
    const float imh = iminfo[0], imw = iminfo[1];
    const float bx1 = c_base[tid][0], by1 = c_base[tid][1];
    const float bx2 = c_base[tid][2], by2 = c_base[tid][3];
    int xlo = max(0, (int)ceilf(-bx1 / 16.f));
    int xhi = min(W_ - 1, (int)ceilf((imw - bx2) / 16.f) - 1);
    int ylo = max(0, (int)ceilf(-by1 / 16.f));
    int yhi = min(H_ - 1, (int)ceilf((imh - by2) / 16.f) - 1);
    int nx = max(0, xhi - xlo + 1), ny = max(0, yhi - ylo + 1);
    s_xlo[tid] = xlo; s_ylo[tid] = ylo; s_nx[tid] = nx;
    s_pre[tid + 1] = nx * ny;
  }
  __syncthreads();
  if (tid == 0) {
    s_pre[0] = 0;
    for (int a = 0; a < A_; a++) s_pre[a + 1] += s_pre[a];
  }
  __syncthreads();
  const int C = s_pre[A_];
  const int stride = gridDim.x * 256;

  for (int t0 = blockIdx.x * 256; t0 < C; t0 += stride) {
    if (tid < 2) s_num[tid] = 0;
    __syncthreads();
    const int t = t0 + tid;
    bool act = false;
    int p = 0, lpos = 0, n = 0;
    uint32_t m = 0;
    if (t < C) {
      int a = 0;
      while (t >= s_pre[a + 1]) a++;
      const int idx = t - s_pre[a];
      const int nx = s_nx[a];
      const int y = s_ylo[a] + idx / nx;
      const int x = s_xlo[a] + (idx - (idx / nx) * nx);
      n = (y * W_ + x) * A_ + a;                 // ORIGINAL index (RNG order)
      const int n2 = a * HW_ + y * W_ + x;       // output-layout index
      const float sx = 16.f * (float)x, sy = 16.f * (float)y;
      const float ax1 = c_base[a][0] + sx, ay1 = c_base[a][1] + sy;
      const float ax2 = c_base[a][2] + sx, ay2 = c_base[a][3] + sy;
      const float aarea = box_area_f(c_base[a][0], c_base[a][1],
                                     c_base[a][2], c_base[a][3]);  // == shifted
      float mo = -1.f;
      int bidx = 0;
      bool best = false;
      for (int k = 0; k < KG_; k++) {
        float ovr = iou_core(ax1, ay1, ax2, ay2, aarea,
                             sgx1[k], sgy1[k], sgx2[k], sgy2[k], sga[k]);
        if (ovr > mo) { mo = ovr; bidx = k; }    // first-argmax (matches jnp)
        best = best || (ovr == sgm[k]);
      }
      int lab = -1;
      if (mo < 0.3f) lab = 0;
      if (best || mo >= 0.7f) lab = 1;
      packed[(size_t)b * N_ + n2] = (bidx << 2) | (lab + 1);
      if (lab >= 0) {
        act = true;
        p = (lab == 1) ? 0 : 1;
        uint32_t y0, y1;
        tf2x32(s_k[2 * p], s_k[2 * p + 1], 0u, (uint32_t)n, y0, y1);
        m = (y0 ^ y1) >> 9;
        lpos = atomicAdd(&s_num[p], 1);
      }
    }
    __syncthreads();
    if (tid < 2 && s_num[tid] > 0)
      s_base[tid] = atomicAdd(&cnt[b * 2 + tid], s_num[tid]);
    __syncthreads();
    if (act) {
      cand[(size_t)(b * 2 + p) * CAP_ + s_base[p] + lpos] =
          ((ull)m << 16) | (ull)(65535 - n);
      atomicAdd(&hist[(b * 2 + p) * 256 + (int)(m >> 15)], 1);
    }
    __syncthreads();
  }

  // ---- last-arrival selection for batch b (release: fence before count) --
  __threadfence();
  if (tid == 0) s_last = (atomicAdd(&done[b], 1) == FB_ - 1);
  __syncthreads();
  if (!s_last) return;
  __threadfence();                         // acquire: see all blocks' writes

  const int cf = cnt[b * 2 + 0], cb = cnt[b * 2 + 1];
  {
    int kf = min(cf, 128);
    int kb = min(cb, 256 - kf);
    if (tid == 0) uw[b] = 1.f / (float)(kf + kb);
  }
  for (int p = 0; p < 2; p++) {
    const int limit = (p == 0) ? 128 : 256 - min(cf, 128);
    const int c = (p == 0) ? cf : cb;
    if (c <= limit) {
      if (tid == 0) Kstar[b * 2 + p] = 0ull;   // keep all (keys always > 0)
      continue;
    }
    if (tid == 0) {
      const int* Hh = hist + (b * 2 + p) * 256;
      int acc = 0, bin = 255, r = 0;
      for (; bin >= 0; bin--) {
        int hv = Hh[bin];
        if (acc + hv >= limit) { r = limit - acc; break; }
        acc += hv;
      }
      s_bin = bin; s_r = r; s_n = 0;
    }
    __syncthreads();
    const uint32_t bin0 = (uint32_t)s_bin;
    const int r0 = s_r;                        // 1-based rank within bin
    const ull* Cc = cand + (size_t)(b * 2 + p) * CAP_;
    for (int i = tid; i < c; i += 256) {
      ull k = Cc[i];
      if ((uint32_t)(k >> 31) == bin0) {       // key bits 31..38 == m>>15
        int pos = atomicAdd(&s_n, 1);
        if (pos < 2048) s_keys[pos] = k;
      }
    }
    __syncthreads();
    const int s = min(s_n, 2048);
    for (int j = tid; j < s; j += 256) {
      ull kj = s_keys[j];
      int rank = 0;
      for (int q = 0; q < s; q++) rank += (s_keys[q] > kj) ? 1 : 0;
      if (rank == r0 - 1) Kstar[b * 2 + p] = kj;   // unique writer
    }
    __syncthreads();
  }
}

// ---------------------------------------------------------------------------
// K4 (R10 verbatim): outputs, vectorized x4, folded disable via K*.
__global__ __launch_bounds__(256) void k_out(const float* __restrict__ gtb,
                                             const float* __restrict__ iminfo,
                                             const int* __restrict__ packed,
                                             const ull* __restrict__ Kstar,
                                             const float* __restrict__ uw,
                                             const uint32_t* __restrict__ keys,
                                             float* __restrict__ out) {
  const int gid = blockIdx.x * 256 + threadIdx.x;  // 0 .. S0_/4-1
  const int e = gid * 4;                           // output-linear base index
  const int w0 = e & 63;
  const int h = (e >> 6) & 63;
  const int a = (e >> 12) % A_;
  const int b = e / (A_ * HW_);

  const float imh = iminfo[0], imw = iminfo[1];
  const float ay1 = c_base[a][1] + 16.f * (float)h;
  const float ay2 = c_base[a][3] + 16.f * (float)h;
  const bool insY = (ay1 >= 0.f) && (ay2 < imh);

  const int4 pk4 = *(const int4*)(packed + e);     // packed[b*N+n2] == packed[e]
  const int pk[4] = {pk4.x, pk4.y, pk4.z, pk4.w};
  const float uwb = uw[b];
  const ull KF_ = Kstar[b * 2 + 0];
  const ull KB_ = Kstar[b * 2 + 1];
  const uint32_t kf0 = keys[b * 4 + 0], kf1 = keys[b * 4 + 1];
  const uint32_t kb0 = keys[b * 4 + 2], kb1 = keys[b * 4 + 3];

  float4 lab4, tx4, ty4, tw4, th4, inw4, oww4;
  float* labp = (float*)&lab4;
  float* txp = (float*)&tx4; float* typ = (float*)&ty4;
  float* twp = (float*)&tw4; float* thp = (float*)&th4;
  float* inwp = (float*)&inw4; float* owwp = (float*)&oww4;

  #pragma unroll
  for (int j = 0; j < 4; j++) {
    const int w = w0 + j;
    const float ax1 = c_base[a][0] + 16.f * (float)w;
    const float ax2 = c_base[a][2] + 16.f * (float)w;
    const bool ins = insY && (ax1 >= 0.f) && (ax2 < imw);
    int lab = (pk[j] & 3) - 1;
    const int g = pk[j] >> 2;
    float tx = 0.f, ty = 0.f, tw = 0.f, th = 0.f;
    if (ins) {
      if (lab >= 0) {                        // folded disable
        const int n = (h * W_ + w) * A_ + a; // ORIGINAL index for RNG
        const int p = (lab == 1) ? 0 : 1;
        uint32_t y0, y1;
        tf2x32(p ? kb0 : kf0, p ? kb1 : kf1, 0u, (uint32_t)n, y0, y1);
        ull key = ((ull)((y0 ^ y1) >> 9) << 16) | (ull)(65535 - n);
        if (key < (p ? KB_ : KF_)) lab = -1;
      }
      const float* gp = gtb + ((size_t)b * KG_ + g) * 5;
      float aw = ax2 - ax1 + 1.f, ah = ay2 - ay1 + 1.f;
      float acx = ax1 + 0.5f * (aw - 1.f), acy = ay1 + 0.5f * (ah - 1.f);
      float gw = gp[2] - gp[0] + 1.f, gh = gp[3] - gp[1] + 1.f;
      float gcx = gp[0] + 0.5f * (gw - 1.f), gcy = gp[1] + 0.5f * (gh - 1.f);
      tx = (gcx - acx) / aw;
      ty = (gcy - acy) / ah;
      tw = logf(gw / aw);
      th = logf(gh / ah);
    }
    labp[j] = ins ? (float)lab : 0.f;
    txp[j] = tx; typ[j] = ty; twp[j] = tw; thp[j] = th;
    inwp[j] = (ins && lab == 1) ? 1.f : 0.f;
    owwp[j] = (ins && lab >= 0) ? uwb : 0.f;
  }

  *(float4*)(out + e) = lab4;                       // labels (B,1,A*H,W)
  float* o1 = out + S0_;
  const size_t toff = (size_t)b * (4 * A_ * HW_) + (4 * a) * HW_ + h * W_ + w0;
  *(float4*)(o1 + toff)           = tx4;
  *(float4*)(o1 + toff + HW_)     = ty4;
  *(float4*)(o1 + toff + 2 * HW_) = tw4;
  *(float4*)(o1 + toff + 3 * HW_) = th4;
  float* o2 = out + S0_ + S1_;
  *(float4*)(o2 + toff)           = inw4;
  *(float4*)(o2 + toff + HW_)     = inw4;
  *(float4*)(o2 + toff + 2 * HW_) = inw4;
  *(float4*)(o2 + toff + 3 * HW_) = inw4;
  float* o3 = out + S0_ + 2 * (size_t)S1_;
  *(float4*)(o3 + toff)           = oww4;
  *(float4*)(o3 + toff + HW_)     = oww4;
  *(float4*)(o3 + toff + 2 * HW_) = oww4;
  *(float4*)(o3 + toff + 3 * HW_) = oww4;
}

// ---------------------------------------------------------------------------
extern "C" void kernel_launch(void* const* d_in, const int* in_sizes, int n_in,
                              void* d_out, int out_size, void* d_ws, size_t ws_size,
                              hipStream_t stream) {
  const float* gtb = (const float*)d_in[1];     // gt_boxes (B,50,5)
  const float* iminfo = (const float*)d_in[2];  // im_info  (B,2)
  float* out = (float*)d_out;

  // workspace layout (~7.9 MB); every segment boundary is 8B-aligned.
  int* packed = (int*)d_ws;                          // B*N
  float* gt_max = (float*)(packed + (size_t)B_ * N_);// B*KG (3200 B)
  float* uw = gt_max + B_ * KG_;                     // B    (64 B)
  uint32_t* keys = (uint32_t*)(uw + B_);             // B*4  (256 B)
  int* cnt = (int*)(keys + B_ * 4);                  // B*2  (128 B)
  int* hist = cnt + B_ * 2;                          // B*2*256 (32 KB)
  int* done = hist + B_ * 2 * 256;                   // B    (64 B)
  ull* Kstar = (ull*)(done + B_);                    // B*2  (256 B)  [8B-aligned]
  ull* cand = Kstar + B_ * 2;                        // B*2*CAP (5.2 MB)

  k_gtmax<<<NGTB_, 256, 0, stream>>>(gtb, iminfo, gt_max, keys, cnt);
  k_fuse<<<dim3(FB_, B_), 256, 0, stream>>>(gtb, iminfo, gt_max, keys,
                                            packed, cand, cnt, hist,
                                            done, Kstar, uw);
  k_out<<<S0_ / 4 / 256, 256, 0, stream>>>(gtb, iminfo, packed, Kstar, uw,
                                           keys, out);
}

// Round 13
// 136.935 us; speedup vs baseline: 2.4969x; 1.7043x over previous
//
#include <hip/hip_runtime.h>
#include <stdint.h>

// ---------------------------------------------------------------------------
// RPN anchor-target layer for MI355X — round 13 (revert to R10, the best
// verified configuration at 137 us).
//
// Measured structural lessons (R11/R12):
//  * grid.sync() ~65-70 us EACH on MI355X (8 XCDs, cross-XCD L2 flush).
//  * per-block __threadfence() last-arrival pattern: +96 us vs stream-ordered
//    launches (k_fuse 42 -> 150 us). Device-scope ordering primitives are
//    ~10x more expensive than the launch gaps they replace. KEEP the
//    4-launch stream-ordered pipeline.
//  * R9 == R10 == 137.1x us with different kernel code: the timed iteration
//    is dominated by harness re-poison fills (256 MiB @ 42 us) + restores +
//    launch overhead; all 4 kernels are individually below the fill cost.
//
// Verified invariants (R6-R10):
//  * ALL IoU math via ONE noinline compiled copy (iou_core + box_area_f) =>
//    bit-identical across call sites (is_best float-equality). DO NOT inline.
//  * JAX partitionable threefry; composite key (m<<16)|(65535-n), n = the
//    ORIGINAL anchor index (h*W+w)*9+a. Keys strictly distinct.
//  * Inside-anchor set == 9 runtime rectangles; compact-candidate selection.
// ---------------------------------------------------------------------------

#define B_   16
#define A_   9
#define H_   64
#define W_   64
#define HW_  (H_*W_)
#define N_   (HW_*A_)      // 36864
#define KG_  50
#define S0_  (B_*A_*HW_)   // labels elems
#define S1_  (B_*4*A_*HW_) // targets / in_w / out_w elems
#define NGTB_ (B_*KG_)     // k_gtmax blocks
#define CAP_  20480        // per-(batch,phase) candidate cap (max possible 18624)
#define NHIST_ (B_*2*256 + B_*2)   // hist + cnt ints to clear

typedef unsigned long long ull;

// base anchors from generate_anchors() (exact: all half-integers cancel)
__constant__ float c_base[A_][4] = {
  { -84.f,  -40.f,  99.f,  55.f},
  {-176.f,  -88.f, 191.f, 103.f},
  {-360.f, -184.f, 375.f, 199.f},
  { -56.f,  -56.f,  71.f,  71.f},
  {-120.f, -120.f, 135.f, 135.f},
  {-248.f, -248.f, 263.f, 263.f},
  { -36.f,  -80.f,  51.f,  95.f},
  { -80.f, -168.f,  95.f, 183.f},
  {-168.f, -344.f, 183.f, 359.f},
};

__device__ __forceinline__ void tf2x32(uint32_t k0, uint32_t k1,
                                       uint32_t x0, uint32_t x1,
                                       uint32_t& o0, uint32_t& o1) {
  const uint32_t ks2 = k0 ^ k1 ^ 0x1BD11BDAu;
  uint32_t ks[3] = {k0, k1, ks2};
  x0 += ks[0]; x1 += ks[1];
  const int R[2][4] = {{13,15,26,6},{17,29,16,24}};
  #pragma unroll
  for (int i = 0; i < 5; i++) {
    #pragma unroll
    for (int j = 0; j < 4; j++) {
      x0 += x1;
      int r = R[i & 1][j];
      x1 = (x1 << r) | (x1 >> (32 - r));
      x1 ^= x0;
    }
    x0 += ks[(i + 1) % 3];
    x1 += ks[(i + 2) % 3] + (uint32_t)(i + 1);
  }
  o0 = x0; o1 = x1;
}

// ---------------------------------------------------------------------------
// Shared noinline numerics: single compiled copy each => cross-kernel
// bit-identity by construction. contract(off) as belt-and-braces.
__device__ __attribute__((noinline))
float box_area_f(float x1, float y1, float x2, float y2) {
#pragma clang fp contract(off)
  return (x2 - x1 + 1.f) * (y2 - y1 + 1.f);
}

__device__ __attribute__((noinline))
float iou_core(float ax1, float ay1, float ax2, float ay2, float aarea,
               float gx1, float gy1, float gx2, float gy2, float garea) {
#pragma clang fp contract(off)
  float ix = fmaxf(fminf(ax2, gx2) - fmaxf(ax1, gx1) + 1.f, 0.f);
  float iy = fmaxf(fminf(ay2, gy2) - fmaxf(ay1, gy1) + 1.f, 0.f);
  float inter = ix * iy;
  return inter / (aarea + garea - inter);
}

// ---------------------------------------------------------------------------
// K1: gt_max — one block per (b,gt), pruned to overlap∩inside rectangle.
// Block 0: threefry keys. Blocks 0..31: clear cnt+hist.
__global__ __launch_bounds__(256) void k_gtmax(const float* __restrict__ gtb,
                                               const float* __restrict__ iminfo,
                                               float* __restrict__ gt_max,
                                               uint32_t* __restrict__ keys,
                                               int* __restrict__ cnt_hist) {
  const int b = blockIdx.x / KG_;
  const int g = blockIdx.x % KG_;
  const int tid = threadIdx.x;
  if (blockIdx.x == 0 && tid < B_) {
    uint32_t k0, k1, kf0, kf1, kb0, kb1;
    tf2x32(0u, 42u, 0u, (uint32_t)tid, k0, k1);  // split(root,16)[b]
    tf2x32(k0, k1, 0u, 0u, kf0, kf1);            // kf
    tf2x32(k0, k1, 0u, 1u, kb0, kb1);            // kb
    keys[tid * 4 + 0] = kf0;
    keys[tid * 4 + 1] = kf1;
    keys[tid * 4 + 2] = kb0;
    keys[tid * 4 + 3] = kb1;
  }
  if (blockIdx.x < 32) {
    const int per = (NHIST_ + 31) / 32;
    const int base = blockIdx.x * per;
    const int lim = min(base + per, NHIST_);
    for (int i = base + tid; i < lim; i += 256) cnt_hist[i] = 0;
  }
  const float* gp = gtb + (b * KG_ + g) * 5;
  const float gx1 = gp[0], gy1 = gp[1], gx2 = gp[2], gy2 = gp[3];
  const float garea = box_area_f(gx1, gy1, gx2, gy2);
  const float imh = iminfo[0], imw = iminfo[1];
  float best = 0.f;
  for (int a = 0; a < A_; a++) {
    const float bx1 = c_base[a][0], by1 = c_base[a][1];
    const float bx2 = c_base[a][2], by2 = c_base[a][3];
    const float aarea = box_area_f(bx1, by1, bx2, by2);  // == shifted (exact ints)
    int xlo = max(0, (int)ceilf(-bx1 / 16.f));
    int xhi = min(W_ - 1, (int)ceilf((imw - bx2) / 16.f) - 1);
    int ylo = max(0, (int)ceilf(-by1 / 16.f));
    int yhi = min(H_ - 1, (int)ceilf((imh - by2) / 16.f) - 1);
    xlo = max(xlo, (int)floorf((gx1 - 1.f - bx2) / 16.f));
    xhi = min(xhi, (int)ceilf((gx2 + 1.f - bx1) / 16.f));
    ylo = max(ylo, (int)floorf((gy1 - 1.f - by2) / 16.f));
    yhi = min(yhi, (int)ceilf((gy2 + 1.f - by1) / 16.f));
    const int nx = xhi - xlo + 1, ny = yhi - ylo + 1;
    if (nx <= 0 || ny <= 0) continue;
    const int lw = (nx <= 1) ? 0 : (32 - __clz(nx - 1));  // 2^lw >= nx
    const int tot = ny << lw;
    const int mask = (1 << lw) - 1;
    for (int t = tid; t < tot; t += 256) {
      const int xi = t & mask;
      if (xi >= nx) continue;
      const int x = xlo + xi;
      const int y = ylo + (t >> lw);
      const float sx = 16.f * (float)x, sy = 16.f * (float)y;
      best = fmaxf(best, iou_core(bx1 + sx, by1 + sy, bx2 + sx, by2 + sy,
                                  aarea, gx1, gy1, gx2, gy2, garea));
    }
  }
  best = fmaxf(best, __shfl_xor(best, 32));
  best = fmaxf(best, __shfl_xor(best, 16));
  best = fmaxf(best, __shfl_xor(best, 8));
  best = fmaxf(best, __shfl_xor(best, 4));
  best = fmaxf(best, __shfl_xor(best, 2));
  best = fmaxf(best, __shfl_xor(best, 1));
  __shared__ float sw[4];
  if ((tid & 63) == 0) sw[tid >> 6] = best;
  __syncthreads();
  if (tid == 0)
    gt_max[b * KG_ + g] = fmaxf(fmaxf(sw[0], sw[1]), fmaxf(sw[2], sw[3]));
}

// ---------------------------------------------------------------------------
// K2: fused labels over the compacted inside-anchor space. Writes ONE packed
// int (amax<<2)|(lab+1) at the OUTPUT-layout index n2 = a*HW+h*W+w (coalesced)
// + candidate list + 256-bin hist. grid (73, B_), grid-stride over C.
__global__ __launch_bounds__(256) void k_fuse(const float* __restrict__ gtb,
                                              const float* __restrict__ iminfo,
                                              const float* __restrict__ gt_max,
                                              const uint32_t* __restrict__ keys,
                                              int* __restrict__ packed,
                                              ull* __restrict__ cand,
                                              int* __restrict__ cnt,
                                              int* __restrict__ hist) {
  __shared__ float sgx1[KG_], sgy1[KG_], sgx2[KG_], sgy2[KG_], sga[KG_], sgm[KG_];
  __shared__ int s_xlo[A_], s_ylo[A_], s_nx[A_], s_pre[A_ + 1];
  __shared__ uint32_t s_k[4];
  __shared__ int s_num[2], s_base[2];
  const int b = blockIdx.y;
  const int tid = threadIdx.x;
  if (tid < KG_) {
    const float* g = gtb + (b * KG_ + tid) * 5;
    float x1 = g[0], y1 = g[1], x2 = g[2], y2 = g[3];
    sgx1[tid] = x1; sgy1[tid] = y1; sgx2[tid] = x2; sgy2[tid] = y2;
    sga[tid] = box_area_f(x1, y1, x2, y2);
    float gm = gt_max[b * KG_ + tid];
    sgm[tid] = (gm == 0.f) ? 1e-5f : gm;
  }
  if (tid < 4) s_k[tid] = keys[b * 4 + tid];
  if (tid < A_) {
    const float imh = iminfo[0], imw = iminfo[1];
    const float bx1 = c_base[tid][0], by1 = c_base[tid][1];
    const float bx2 = c_base[tid][2], by2 = c_base[tid][3];
    int xlo = max(0, (int)ceilf(-bx1 / 16.f));
    int xhi = min(W_ - 1, (int)ceilf((imw - bx2) / 16.f) - 1);
    int ylo = max(0, (int)ceilf(-by1 / 16.f));
    int yhi = min(H_ - 1, (int)ceilf((imh - by2) / 16.f) - 1);
    int nx = max(0, xhi - xlo + 1), ny = max(0, yhi - ylo + 1);
    s_xlo[tid] = xlo; s_ylo[tid] = ylo; s_nx[tid] = nx;
    s_pre[tid + 1] = nx * ny;
  }
  __syncthreads();
  if (tid == 0) {
    s_pre[0] = 0;
    for (int a = 0; a < A_; a++) s_pre[a + 1] += s_pre[a];
  }
  __syncthreads();
  const int C = s_pre[A_];
  const int stride = gridDim.x * 256;

  for (int t0 = blockIdx.x * 256; t0 < C; t0 += stride) {
    if (tid < 2) s_num[tid] = 0;
    __syncthreads();
    const int t = t0 + tid;
    bool act = false;
    int p = 0, lpos = 0, n = 0;
    uint32_t m = 0;
    if (t < C) {
      int a = 0;
      while (t >= s_pre[a + 1]) a++;
      const int idx = t - s_pre[a];
      const int nx = s_nx[a];
      const int y = s_ylo[a] + idx / nx;
      const int x = s_xlo[a] + (idx - (idx / nx) * nx);
      n = (y * W_ + x) * A_ + a;                 // ORIGINAL index (RNG order)
      const int n2 = a * HW_ + y * W_ + x;       // output-layout index
      const float sx = 16.f * (float)x, sy = 16.f * (float)y;
      const float ax1 = c_base[a][0] + sx, ay1 = c_base[a][1] + sy;
      const float ax2 = c_base[a][2] + sx, ay2 = c_base[a][3] + sy;
      const float aarea = box_area_f(c_base[a][0], c_base[a][1],
                                     c_base[a][2], c_base[a][3]);  // == shifted
      float mo = -1.f;
      int bidx = 0;
      bool best = false;
      for (int k = 0; k < KG_; k++) {
        float ovr = iou_core(ax1, ay1, ax2, ay2, aarea,
                             sgx1[k], sgy1[k], sgx2[k], sgy2[k], sga[k]);
        if (ovr > mo) { mo = ovr; bidx = k; }    // first-argmax (matches jnp)
        best = best || (ovr == sgm[k]);
      }
      int lab = -1;
      if (mo < 0.3f) lab = 0;
      if (best || mo >= 0.7f) lab = 1;
      packed[(size_t)b * N_ + n2] = (bidx << 2) | (lab + 1);
      if (lab >= 0) {
        act = true;
        p = (lab == 1) ? 0 : 1;
        uint32_t y0, y1;
        tf2x32(s_k[2 * p], s_k[2 * p + 1], 0u, (uint32_t)n, y0, y1);
        m = (y0 ^ y1) >> 9;
        lpos = atomicAdd(&s_num[p], 1);
      }
    }
    __syncthreads();
    if (tid < 2 && s_num[tid] > 0)
      s_base[tid] = atomicAdd(&cnt[b * 2 + tid], s_num[tid]);
    __syncthreads();
    if (act) {
      cand[(size_t)(b * 2 + p) * CAP_ + s_base[p] + lpos] =
          ((ull)m << 16) | (ull)(65535 - n);
      atomicAdd(&hist[(b * 2 + p) * 256 + (int)(m >> 15)], 1);
    }
    __syncthreads();
  }
}

// ---------------------------------------------------------------------------
// K3: per-(b,phase) cutoff K*. Bin-pick + gather + exact rank. 32 blocks.
__global__ __launch_bounds__(256) void k_select(const ull* __restrict__ cand,
                                                const int* __restrict__ cnt,
                                                const int* __restrict__ hist,
                                                ull* __restrict__ Kstar,
                                                float* __restrict__ uw) {
  const int b = blockIdx.x >> 1, p = blockIdx.x & 1;
  const int tid = threadIdx.x;
  __shared__ ull s_keys[2048];
  __shared__ int s_bin, s_r, s_n;
  const int cf = cnt[b * 2 + 0], cb = cnt[b * 2 + 1];
  const int limit = (p == 0) ? 128 : 256 - min(cf, 128);
  const int c = (p == 0) ? cf : cb;
  if (p == 1 && tid == 0) {
    int kf = min(cf, 128);
    int kb = min(cb, 256 - kf);
    uw[b] = 1.f / (float)(kf + kb);
  }
  if (c <= limit) {
    if (tid == 0) Kstar[b * 2 + p] = 0ull;   // keep all (keys always > 0)
    return;
  }
  if (tid == 0) {
    const int* Hh = hist + (b * 2 + p) * 256;
    int acc = 0, bin = 255, r = 0;
    for (; bin >= 0; bin--) {
      int hv = Hh[bin];
      if (acc + hv >= limit) { r = limit - acc; break; }
      acc += hv;
    }
    s_bin = bin; s_r = r; s_n = 0;
  }
  __syncthreads();
  const uint32_t bin0 = (uint32_t)s_bin;
  const int r0 = s_r;                        // 1-based rank within bin
  const ull* C = cand + (size_t)(b * 2 + p) * CAP_;
  for (int i = tid; i < c; i += 256) {
    ull k = C[i];
    if ((uint32_t)(k >> 31) == bin0) {       // key bits 31..38 == m>>15
      int pos = atomicAdd(&s_n, 1);
      if (pos < 2048) s_keys[pos] = k;
    }
  }
  __syncthreads();
  const int s = min(s_n, 2048);
  for (int j = tid; j < s; j += 256) {
    ull kj = s_keys[j];
    int rank = 0;
    for (int q = 0; q < s; q++) rank += (s_keys[q] > kj) ? 1 : 0;
    if (rank == r0 - 1) Kstar[b * 2 + p] = kj;   // unique writer (keys distinct)
  }
}

// ---------------------------------------------------------------------------
// K4: outputs, vectorized x4 (int4/float4), folded disable via K*.
__global__ __launch_bounds__(256) void k_out(const float* __restrict__ gtb,
                                             const float* __restrict__ iminfo,
                                             const int* __restrict__ packed,
                                             const ull* __restrict__ Kstar,
                                             const float* __restrict__ uw,
                                             const uint32_t* __restrict__ keys,
                                             float* __restrict__ out) {
  const int gid = blockIdx.x * 256 + threadIdx.x;  // 0 .. S0_/4-1
  const int e = gid * 4;                           // output-linear base index
  const int w0 = e & 63;
  const int h = (e >> 6) & 63;
  const int a = (e >> 12) % A_;
  const int b = e / (A_ * HW_);

  const float imh = iminfo[0], imw = iminfo[1];
  const float ay1 = c_base[a][1] + 16.f * (float)h;
  const float ay2 = c_base[a][3] + 16.f * (float)h;
  const bool insY = (ay1 >= 0.f) && (ay2 < imh);

  const int4 pk4 = *(const int4*)(packed + e);     // packed[b*N+n2] == packed[e]
  const int pk[4] = {pk4.x, pk4.y, pk4.z, pk4.w};
  const float uwb = uw[b];
  const ull KF_ = Kstar[b * 2 + 0];
  const ull KB_ = Kstar[b * 2 + 1];
  const uint32_t kf0 = keys[b * 4 + 0], kf1 = keys[b * 4 + 1];
  const uint32_t kb0 = keys[b * 4 + 2], kb1 = keys[b * 4 + 3];

  float4 lab4, tx4, ty4, tw4, th4, inw4, oww4;
  float* labp = (float*)&lab4;
  float* txp = (float*)&tx4; float* typ = (float*)&ty4;
  float* twp = (float*)&tw4; float* thp = (float*)&th4;
  float* inwp = (float*)&inw4; float* owwp = (float*)&oww4;

  #pragma unroll
  for (int j = 0; j < 4; j++) {
    const int w = w0 + j;
    const float ax1 = c_base[a][0] + 16.f * (float)w;
    const float ax2 = c_base[a][2] + 16.f * (float)w;
    const bool ins = insY && (ax1 >= 0.f) && (ax2 < imw);
    int lab = (pk[j] & 3) - 1;
    const int g = pk[j] >> 2;
    float tx = 0.f, ty = 0.f, tw = 0.f, th = 0.f;
    if (ins) {
      if (lab >= 0) {                        // folded disable
        const int n = (h * W_ + w) * A_ + a; // ORIGINAL index for RNG
        const int p = (lab == 1) ? 0 : 1;
        uint32_t y0, y1;
        tf2x32(p ? kb0 : kf0, p ? kb1 : kf1, 0u, (uint32_t)n, y0, y1);
        ull key = ((ull)((y0 ^ y1) >> 9) << 16) | (ull)(65535 - n);
        if (key < (p ? KB_ : KF_)) lab = -1;
      }
      const float* gp = gtb + ((size_t)b * KG_ + g) * 5;
      float aw = ax2 - ax1 + 1.f, ah = ay2 - ay1 + 1.f;
      float acx = ax1 + 0.5f * (aw - 1.f), acy = ay1 + 0.5f * (ah - 1.f);
      float gw = gp[2] - gp[0] + 1.f, gh = gp[3] - gp[1] + 1.f;
      float gcx = gp[0] + 0.5f * (gw - 1.f), gcy = gp[1] + 0.5f * (gh - 1.f);
      tx = (gcx - acx) / aw;
      ty = (gcy - acy) / ah;
      tw = logf(gw / aw);
      th = logf(gh / ah);
    }
    labp[j] = ins ? (float)lab : 0.f;
    txp[j] = tx; typ[j] = ty; twp[j] = tw; thp[j] = th;
    inwp[j] = (ins && lab == 1) ? 1.f : 0.f;
    owwp[j] = (ins && lab >= 0) ? uwb : 0.f;
  }

  *(float4*)(out + e) = lab4;                       // labels (B,1,A*H,W)
  float* o1 = out + S0_;
  const size_t toff = (size_t)b * (4 * A_ * HW_) + (4 * a) * HW_ + h * W_ + w0;
  *(float4*)(o1 + toff)           = tx4;
  *(float4*)(o1 + toff + HW_)     = ty4;
  *(float4*)(o1 + toff + 2 * HW_) = tw4;
  *(float4*)(o1 + toff + 3 * HW_) = th4;
  float* o2 = out + S0_ + S1_;
  *(float4*)(o2 + toff)           = inw4;
  *(float4*)(o2 + toff + HW_)     = inw4;
  *(float4*)(o2 + toff + 2 * HW_) = inw4;
  *(float4*)(o2 + toff + 3 * HW_) = inw4;
  float* o3 = out + S0_ + 2 * (size_t)S1_;
  *(float4*)(o3 + toff)           = oww4;
  *(float4*)(o3 + toff + HW_)     = oww4;
  *(float4*)(o3 + toff + 2 * HW_) = oww4;
  *(float4*)(o3 + toff + 3 * HW_) = oww4;
}

// ---------------------------------------------------------------------------
extern "C" void kernel_launch(void* const* d_in, const int* in_sizes, int n_in,
                              void* d_out, int out_size, void* d_ws, size_t ws_size,
                              hipStream_t stream) {
  const float* gtb = (const float*)d_in[1];     // gt_boxes (B,50,5)
  const float* iminfo = (const float*)d_in[2];  // im_info  (B,2)
  float* out = (float*)d_out;

  // workspace layout (~7.9 MB); every segment is 8B-aligned.
  int* packed = (int*)d_ws;                          // B*N
  float* gt_max = (float*)(packed + (size_t)B_ * N_);// B*KG (3200 B)
  float* uw = gt_max + B_ * KG_;                     // B    (64 B)
  uint32_t* keys = (uint32_t*)(uw + B_);             // B*4  (256 B)
  int* cnt = (int*)(keys + B_ * 4);                  // B*2  (128 B)
  int* hist = cnt + B_ * 2;                          // B*2*256 (32 KB)
  ull* Kstar = (ull*)(hist + B_ * 2 * 256);          // B*2  (256 B)
  ull* cand = Kstar + B_ * 2;                        // B*2*CAP (5.2 MB)

  k_gtmax<<<NGTB_, 256, 0, stream>>>(gtb, iminfo, gt_max, keys, cnt);
  k_fuse<<<dim3(73, B_), 256, 0, stream>>>(gtb, iminfo, gt_max, keys,
                                           packed, cand, cnt, hist);
  k_select<<<B_ * 2, 256, 0, stream>>>(cand, cnt, hist, Kstar, uw);
  k_out<<<S0_ / 4 / 256, 256, 0, stream>>>(gtb, iminfo, packed, Kstar, uw,
                                           keys, out);
}